// Round 6
// baseline (283.938 us; speedup 1.0000x reference)
//
#include <hip/hip_runtime.h>
#include <stdint.h>

typedef unsigned short u16;
typedef __bf16 bf16x8 __attribute__((ext_vector_type(8)));
typedef float f32x4 __attribute__((ext_vector_type(4)));

#define MM 2
#define NN 8
#define CC 1024
#define DD 256
#define BB 32
#define SS 512

__device__ __forceinline__ u16 f2bf(float f) {
  uint32_t u = __float_as_uint(f);
  u += 0x7FFFu + ((u >> 16) & 1u);   // round-to-nearest-even
  return (u16)(u >> 16);
}

__device__ __forceinline__ uint32_t pack2(float a, float b) {
  return (uint32_t)f2bf(a) | ((uint32_t)f2bf(b) << 16);
}

__device__ __forceinline__ void async16(const void* g, void* l) {
  __builtin_amdgcn_global_load_lds(
      (const __attribute__((address_space(1))) uint32_t*)g,
      (__attribute__((address_space(3))) uint32_t*)l, 16, 0, 0);
}

// ---------------- prep: transpose+convert both weight tensors ----------------
// src fp32 [16][K][N] -> dst bf16 [16][N][K]; tile 64(K) x 32(N). (r4 version)
__global__ __launch_bounds__(256) void prep_w(
    const float* __restrict__ dw, u16* __restrict__ wdT,
    const float* __restrict__ uw, u16* __restrict__ wuT) {
  __shared__ float tile[64][33];
  int bid = blockIdx.x;
  const float* src; u16* dst; int K, N, tk, tn;
  if (bid < 2048) {
    K = CC; N = DD;
    const int slab = bid >> 7, t = bid & 127;   // 16 x 8 tiles per slab
    tk = t >> 3; tn = t & 7;
    src = dw + (size_t)slab * K * N;
    dst = wdT + (size_t)slab * K * N;
  } else {
    bid -= 2048;
    K = DD; N = CC;
    const int slab = bid >> 7, t = bid & 127;   // 4 x 32 tiles per slab
    tk = t >> 5; tn = t & 31;
    src = uw + (size_t)slab * K * N;
    dst = wuT + (size_t)slab * K * N;
  }
  const int k0 = tk * 64, n0 = tn * 32;
  const int tx = threadIdx.x & 31, ty = threadIdx.x >> 5;
#pragma unroll
  for (int i = 0; i < 64; i += 8)
    tile[ty + i][tx] = src[(size_t)(k0 + ty + i) * N + n0 + tx];
  __syncthreads();
  uint32_t* dst32 = reinterpret_cast<uint32_t*>(dst);
#pragma unroll
  for (int i = 0; i < 32; i += 8) {
    const int nr = ty + i;
    dst32[((size_t)(n0 + nr) * K + k0) / 2 + tx] =
        pack2(tile[2 * tx][nr], tile[2 * tx + 1][nr]);
  }
}

// ---------------- k1: z = silu(x @ Wd + b) -> bf16 [pair][S][D] -------------
// 128s x 128d tiles, 512 blocks, 256 thr (4 waves 2x2), BK=64, 16 iters.
// LDS 64 KB -> 2 blocks/CU (cross-block overlap hides barrier drain, m97/m114).
// A: x fp32 loaded to regs, packed to bf16 in-loop (overlaps across blocks).
// B: Wd^T via global_load_lds, chunk-XOR swizzle (slot = c ^ (row&7)).
__global__ __launch_bounds__(256, 2) void k1_down(
    const float* __restrict__ x, const u16* __restrict__ wdT,
    const float* __restrict__ db, const int* __restrict__ eidx,
    u16* __restrict__ z) {
  __shared__ __align__(16) u16 smA[2][128 * 64];   // 2 x 16 KB
  __shared__ __align__(16) u16 smB[2][128 * 64];   // 2 x 16 KB

  // XCD-grouped decode: XCD owns 4 b's x 2 m x 4 stiles x 2 dtiles
  const int id = blockIdx.x;
  const int xcd = id & 7;
  const int j6 = id >> 3;            // 0..63
  const int b = xcd * 4 + (j6 & 3);
  const int rest = j6 >> 2;          // 0..15
  const int m = rest & 1;
  const int stile = (rest >> 1) & 3;
  const int dtile = rest >> 3;       // 0..1
  const int pair = m * BB + b;
  const int e = eidx[pair];
  const int s0 = stile * 128;
  const int d0 = dtile * 128;

  const int tid = threadIdx.x;
  const int lane = tid & 63;
  const int wave = tid >> 6;         // 0..3
  const int quad = lane >> 4;
  const int l16 = lane & 15;
  const int fxr = l16 & 7;

  const int wr = (wave >> 1) * 64;   // s rows
  const int wc = (wave & 1) * 64;    // d cols (within 128 tile)

  const u16* Bd = wdT + (size_t)(m * NN + e) * DD * CC + (size_t)d0 * CC;

  const float* bias_p = db + (size_t)(m * NN + e) * DD + d0;
  float biasr[4];
#pragma unroll
  for (int j = 0; j < 4; ++j) biasr[j] = bias_p[wc + j * 16 + l16];

  // A pack: thread covers row tid>>1, chunks ac0..ac0+3 (32 floats, 128 B)
  const int arow = tid >> 1;
  const int ac0 = (tid & 1) * 4;
  const float* gAx = x + ((size_t)b * SS + s0 + arow) * CC + ac0 * 8;
  int lAs[4];
#pragma unroll
  for (int c = 0; c < 4; ++c)
    lAs[c] = arow * 64 + (((ac0 + c) ^ (arow & 7)) * 8);

  // B staging: wave stages 32 rows (4 async16 of 8 rows each)
  const int r_l = lane >> 3;
  const int sx = (lane & 7) ^ r_l;
  const u16* gBd = Bd + (size_t)(wave * 32 + r_l) * CC + sx * 8;

  f32x4 acc[4][4];
#pragma unroll
  for (int i = 0; i < 4; ++i)
#pragma unroll
    for (int j = 0; j < 4; ++j) acc[i][j] = (f32x4){0.f, 0.f, 0.f, 0.f};

  // ---- prologue: A(0) load+pack, B(0) asyncs ----
  {
    float4 a[8];
#pragma unroll
    for (int c = 0; c < 4; ++c) {
      a[2 * c]     = *reinterpret_cast<const float4*>(gAx + c * 8);
      a[2 * c + 1] = *reinterpret_cast<const float4*>(gAx + c * 8 + 4);
    }
#pragma unroll
    for (int s = 0; s < 4; ++s)
      async16(gBd + (size_t)(s * 8) * CC, &smB[0][(wave * 32 + s * 8) * 64]);
#pragma unroll
    for (int c = 0; c < 4; ++c)
      *reinterpret_cast<uint4*>(&smA[0][lAs[c]]) =
          make_uint4(pack2(a[2 * c].x, a[2 * c].y), pack2(a[2 * c].z, a[2 * c].w),
                     pack2(a[2 * c + 1].x, a[2 * c + 1].y),
                     pack2(a[2 * c + 1].z, a[2 * c + 1].w));
  }
  asm volatile("s_waitcnt vmcnt(0) lgkmcnt(0)" ::: "memory");
  __builtin_amdgcn_s_barrier();

  // ---- K = 1024, 16 iters of BK=64 ----
  for (int kk = 0; kk < 16; ++kk) {
    const int cur = kk & 1, nxt = cur ^ 1;
    float4 a[8];
    if (kk < 15) {
      const float* gA = gAx + (kk + 1) * 64;
#pragma unroll
      for (int c = 0; c < 4; ++c) {
        a[2 * c]     = *reinterpret_cast<const float4*>(gA + c * 8);
        a[2 * c + 1] = *reinterpret_cast<const float4*>(gA + c * 8 + 4);
      }
      const int ko = (kk + 1) * 64;
#pragma unroll
      for (int s = 0; s < 4; ++s)
        async16(gBd + (size_t)(s * 8) * CC + ko, &smB[nxt][(wave * 32 + s * 8) * 64]);
    }
#pragma unroll
    for (int h = 0; h < 2; ++h) {
      bf16x8 af[4], bfr[4];
#pragma unroll
      for (int i = 0; i < 4; ++i)
        af[i] = *reinterpret_cast<const bf16x8*>(
            &smA[cur][(wr + i * 16 + l16) * 64 + ((h * 4 + quad) ^ fxr) * 8]);
#pragma unroll
      for (int j = 0; j < 4; ++j)
        bfr[j] = *reinterpret_cast<const bf16x8*>(
            &smB[cur][(wc + j * 16 + l16) * 64 + ((h * 4 + quad) ^ fxr) * 8]);
      __builtin_amdgcn_s_setprio(1);
#pragma unroll
      for (int i = 0; i < 4; ++i)
#pragma unroll
        for (int j = 0; j < 4; ++j)
          acc[i][j] = __builtin_amdgcn_mfma_f32_16x16x32_bf16(af[i], bfr[j], acc[i][j], 0, 0, 0);
      __builtin_amdgcn_s_setprio(0);
    }
    if (kk < 15) {
#pragma unroll
      for (int c = 0; c < 4; ++c)
        *reinterpret_cast<uint4*>(&smA[nxt][lAs[c]]) =
            make_uint4(pack2(a[2 * c].x, a[2 * c].y), pack2(a[2 * c].z, a[2 * c].w),
                       pack2(a[2 * c + 1].x, a[2 * c + 1].y),
                       pack2(a[2 * c + 1].z, a[2 * c + 1].w));
    }
    asm volatile("s_waitcnt vmcnt(0) lgkmcnt(0)" ::: "memory");
    __builtin_amdgcn_s_barrier();
  }

  // ---- epilogue: silu+bias -> LDS bounce (32 KB, reuses smA) -> coalesced z ----
  u16* bounce = &smA[0][0];
#pragma unroll
  for (int j = 0; j < 4; ++j) {
#pragma unroll
    for (int i = 0; i < 4; ++i) {
#pragma unroll
      for (int r = 0; r < 4; ++r) {
        const int row = wr + i * 16 + quad * 4 + r;
        const int dl = wc + j * 16 + l16;
        float v = acc[i][j][r] + biasr[j];
        v = v / (1.f + __expf(-v));
        bounce[row * 128 + (((dl >> 3) ^ (row & 7)) * 8) + (dl & 7)] = f2bf(v);
      }
    }
  }
  asm volatile("s_waitcnt lgkmcnt(0)" ::: "memory");
  __builtin_amdgcn_s_barrier();
  const int orow = tid >> 1, ohalf = tid & 1;
  u16* gz = z + ((size_t)pair * SS + s0 + orow) * DD + d0 + ohalf * 64;
#pragma unroll
  for (int n = 0; n < 8; ++n) {
    const int c = ohalf * 8 + n;
    uint4 v = *reinterpret_cast<uint4*>(
        &bounce[orow * 128 + ((c ^ (orow & 7)) * 8)]);
    *reinterpret_cast<uint4*>(gz + n * 8) = v;
  }
}

// ---------------- k2: out = z @ Wu -------------------------------------------
// 128s x 128c tiles, 2048 blocks, 256 thr (4 waves 2x2), K=256 (4 iters BK=64).
// LDS 64 KB -> 2 blocks/CU. Both A (z) and B (Wu^T) via global_load_lds.
__global__ __launch_bounds__(256, 2) void k2_up(
    const u16* __restrict__ z, const u16* __restrict__ wuT,
    const int* __restrict__ eidx, float* __restrict__ out) {
  __shared__ __align__(16) u16 smA[2][128 * 64];
  __shared__ __align__(16) u16 smB[2][128 * 64];

  const int id = blockIdx.x;
  const int xcd = id & 7;
  const int j8 = id >> 3;            // 0..255
  const int b = xcd * 4 + (j8 & 3);
  const int rest = j8 >> 2;          // 0..63
  const int m = rest & 1;
  const int stile = (rest >> 1) & 3;
  const int ctile = rest >> 3;       // 0..7
  const int pair = m * BB + b;
  const int e = eidx[pair];
  const int s0 = stile * 128;
  const int c0 = ctile * 128;

  const int tid = threadIdx.x;
  const int lane = tid & 63;
  const int wave = tid >> 6;         // 0..3
  const int quad = lane >> 4;
  const int l16 = lane & 15;
  const int fxr = l16 & 7;

  const int wr = (wave >> 1) * 64;   // s rows
  const int wc = (wave & 1) * 64;    // c cols (within 128 tile)

  const u16* Bu = wuT + (size_t)(m * NN + e) * CC * DD + (size_t)c0 * DD;

  const int r_l = lane >> 3;
  const int sx = (lane & 7) ^ r_l;
  const u16* gA = z + ((size_t)pair * SS + s0 + wave * 32 + r_l) * DD + sx * 8;
  const u16* gB = Bu + (size_t)(wave * 32 + r_l) * DD + sx * 8;

  f32x4 acc[4][4];
#pragma unroll
  for (int i = 0; i < 4; ++i)
#pragma unroll
    for (int j = 0; j < 4; ++j) acc[i][j] = (f32x4){0.f, 0.f, 0.f, 0.f};

  // ---- prologue: stage A(0), B(0) ----
#pragma unroll
  for (int s = 0; s < 4; ++s) {
    async16(gA + (size_t)(s * 8) * DD, &smA[0][(wave * 32 + s * 8) * 64]);
    async16(gB + (size_t)(s * 8) * DD, &smB[0][(wave * 32 + s * 8) * 64]);
  }
  asm volatile("s_waitcnt vmcnt(0) lgkmcnt(0)" ::: "memory");
  __builtin_amdgcn_s_barrier();

  // ---- K = 256, 4 iters of BK=64 ----
#pragma unroll
  for (int g = 0; g < 4; ++g) {
    const int cur = g & 1, nxt = cur ^ 1;
    if (g < 3) {
      const int ko = (g + 1) * 64;
#pragma unroll
      for (int s = 0; s < 4; ++s) {
        async16(gA + (size_t)(s * 8) * DD + ko, &smA[nxt][(wave * 32 + s * 8) * 64]);
        async16(gB + (size_t)(s * 8) * DD + ko, &smB[nxt][(wave * 32 + s * 8) * 64]);
      }
    }
#pragma unroll
    for (int h = 0; h < 2; ++h) {
      bf16x8 af[4], bfr[4];
#pragma unroll
      for (int i = 0; i < 4; ++i)
        af[i] = *reinterpret_cast<const bf16x8*>(
            &smA[cur][(wr + i * 16 + l16) * 64 + ((h * 4 + quad) ^ fxr) * 8]);
#pragma unroll
      for (int j = 0; j < 4; ++j)
        bfr[j] = *reinterpret_cast<const bf16x8*>(
            &smB[cur][(wc + j * 16 + l16) * 64 + ((h * 4 + quad) ^ fxr) * 8]);
      __builtin_amdgcn_s_setprio(1);
#pragma unroll
      for (int i = 0; i < 4; ++i)
#pragma unroll
        for (int j = 0; j < 4; ++j)
          acc[i][j] = __builtin_amdgcn_mfma_f32_16x16x32_bf16(af[i], bfr[j], acc[i][j], 0, 0, 0);
      __builtin_amdgcn_s_setprio(0);
    }
    if (g < 3) {
      asm volatile("s_waitcnt vmcnt(0) lgkmcnt(0)" ::: "memory");
      __builtin_amdgcn_s_barrier();
    }
  }

  // ---- epilogue: fp32 stores ----
  float* ob = out + ((size_t)pair * SS + s0) * CC;
#pragma unroll
  for (int j = 0; j < 4; ++j) {
    const int c = c0 + wc + j * 16 + l16;
#pragma unroll
    for (int i = 0; i < 4; ++i) {
      const int sr = wr + i * 16 + quad * 4;
#pragma unroll
      for (int r = 0; r < 4; ++r)
        ob[(size_t)(sr + r) * CC + c] = acc[i][j][r];
    }
  }
}

extern "C" void kernel_launch(void* const* d_in, const int* in_sizes, int n_in,
                              void* d_out, int out_size, void* d_ws, size_t ws_size,
                              hipStream_t stream) {
  const float* x  = (const float*)d_in[0];  // [B,S,C]
  const int* eidx = (const int*)d_in[1];    // [M,B]
  const float* dw = (const float*)d_in[2];  // [M,N,C,D]
  const float* db = (const float*)d_in[3];  // [M,N,D]
  const float* uw = (const float*)d_in[4];  // [M,N,D,C]
  float* out = (float*)d_out;               // [M,B,S,C]

  char* ws = (char*)d_ws;
  u16* wdT = (u16*)(ws);                                   //  8 MB: [M,N,D,C] bf16
  u16* wuT = (u16*)(ws + (size_t)8 * 1024 * 1024);         //  8 MB: [M,N,C,D] bf16
  u16* zbf = (u16*)(ws + (size_t)16 * 1024 * 1024);        // 16 MB: [M*B,S,D] bf16

  prep_w<<<dim3(4096), dim3(256), 0, stream>>>(dw, wdT, uw, wuT);
  k1_down<<<dim3(512), dim3(256), 0, stream>>>(x, wdT, db, eidx, zbf);
  k2_up<<<dim3(2048), dim3(256), 0, stream>>>(zbf, wuT, eidx, out);
}